// Round 15
// baseline (634.065 us; speedup 1.0000x reference)
//
#include <hip/hip_runtime.h>

#define F 128
#define PSH 13            // src partition = s >> 13 (8192 nodes = 2MB bf16), p in [0,13)
#define NP 13
#define DPW 10            // dst rows per wave; 8 waves * 10 * 512B = 40KB LDS -> 4 blocks/CU

typedef __attribute__((ext_vector_type(8))) short bf16x8;
typedef __attribute__((ext_vector_type(4))) float f32x4;

// ---------------- bf16 helpers ----------------

__device__ __forceinline__ unsigned short f32_to_bf16_rne(float x) {
    unsigned u = __float_as_uint(x);
    unsigned r = (u + 0x7fffu + ((u >> 16) & 1u)) >> 16;   // round to nearest even
    return (unsigned short)r;
}

__device__ __forceinline__ float bfhi(unsigned v) { return __uint_as_float(v & 0xffff0000u); }
__device__ __forceinline__ float bflo(unsigned v) { return __uint_as_float(v << 16); }

// ---------------- converts ----------------

__global__ __launch_bounds__(256) void cvtx_kernel(const float4* __restrict__ x4,
                                                   ushort4* __restrict__ xb4, long n4) {
    long stride = (long)gridDim.x * 256;
    for (long i = blockIdx.x * 256 + threadIdx.x; i < n4; i += stride) {
        float4 v = x4[i];
        ushort4 o;
        o.x = f32_to_bf16_rne(v.x);
        o.y = f32_to_bf16_rne(v.y);
        o.z = f32_to_bf16_rne(v.z);
        o.w = f32_to_bf16_rne(v.w);
        xb4[i] = o;
    }
}

__global__ __launch_bounds__(128) void cvtw_kernel(const float* __restrict__ W,
                                                   unsigned short* __restrict__ Wt) {
    int c = blockIdx.x, k = threadIdx.x;
    Wt[c * F + k] = f32_to_bf16_rne(W[k * F + c]);
}

// ---------------- MFMA GEMM ----------------

__global__ __launch_bounds__(256) void gemm_mfma(const unsigned short* __restrict__ hb,
                                                 const unsigned short* __restrict__ Wt,
                                                 unsigned short* __restrict__ outb, int n) {
    __shared__ unsigned short sm[4][16][F + 4];
    const int tid = threadIdx.x;
    const int w = tid >> 6, lane = tid & 63;
    const int r = lane & 15, kg = lane >> 4;
    const long base = (long)blockIdx.x * 64 + w * 16;

    int arow = (int)(base + r);
    if (arow >= n) arow = n - 1;
    const bf16x8* __restrict__ arowp = (const bf16x8*)(hb + (size_t)arow * F);

    f32x4 acc[8] = {};
    #pragma unroll
    for (int c = 0; c < 4; c++) {
        bf16x8 a = arowp[c * 4 + kg];
        #pragma unroll
        for (int t = 0; t < 8; t++) {
            bf16x8 b = *(const bf16x8*)(Wt + (size_t)(t * 16 + r) * F + c * 32 + kg * 8);
            acc[t] = __builtin_amdgcn_mfma_f32_16x16x32_bf16(a, b, acc[t], 0, 0, 0);
        }
    }

    #pragma unroll
    for (int t = 0; t < 8; t++)
        #pragma unroll
        for (int j = 0; j < 4; j++)
            sm[w][kg * 4 + j][t * 16 + r] = f32_to_bf16_rne(acc[t][j]);
    #pragma unroll
    for (int it = 0; it < 4; it++) {
        int row = it * 4 + kg;
        long grow = base + row;
        if (grow < n) {
            uint4 v = *(uint4*)&sm[w][row][r * 8];
            *(uint4*)(outb + (size_t)grow * F + r * 8) = v;
        }
    }
}

// ---------------- build: edges binned by (wq = d/DPW, src partition) ----------

__global__ __launch_bounds__(256) void count16_kernel(const int* __restrict__ src,
                                                      const int* __restrict__ dst,
                                                      int* __restrict__ cnt,
                                                      int* __restrict__ cntd, int e) {
    int i = blockIdx.x * 256 + threadIdx.x;
    if (i >= e) return;
    int s = src[i], d = dst[i];
    unsigned p = (unsigned)s >> PSH;
    atomicAdd(&cnt[(size_t)((unsigned)d / DPW) * NP + p], 1);
    atomicAdd(&cntd[d], 1);
}

__global__ __launch_bounds__(256) void dinv_kernel(const int* __restrict__ cnt,
                                                   float* __restrict__ dinv, int n) {
    int i = blockIdx.x * 256 + threadIdx.x;
    if (i < n) dinv[i] = rsqrtf((float)(cnt[i] + 1));
}

// 3-phase coalesced scan over M elements
__global__ __launch_bounds__(256) void scanA_kernel(const int* __restrict__ cnt,
                                                    int* __restrict__ bsum, int M) {
    __shared__ int sm[256];
    int t = threadIdx.x;
    int i = blockIdx.x * 256 + t;
    int v = (i < M) ? cnt[i] : 0;
    sm[t] = v;
    __syncthreads();
    for (int d = 128; d > 0; d >>= 1) {
        if (t < d) sm[t] += sm[t + d];
        __syncthreads();
    }
    if (t == 0) bsum[blockIdx.x] = sm[0];
}

__global__ __launch_bounds__(1024) void scanB_kernel(const int* __restrict__ bsum,
                                                     int* __restrict__ bpre,
                                                     int* __restrict__ offs, int nb, int M) {
    __shared__ int sm[1024];
    int t = threadIdx.x;
    int chunk = (nb + 1023) >> 10;
    int b = t * chunk;
    int e = b + chunk; if (e > nb) e = nb;
    int s = 0;
    for (int i = b; i < e; i++) s += bsum[i];
    sm[t] = s;
    __syncthreads();
    for (int d = 1; d < 1024; d <<= 1) {
        int v = 0;
        if (t >= d) v = sm[t - d];
        __syncthreads();
        if (t >= d) sm[t] += v;
        __syncthreads();
    }
    int run = (t == 0) ? 0 : sm[t - 1];
    for (int i = b; i < e; i++) { bpre[i] = run; run += bsum[i]; }
    if (t == 1023) offs[M] = sm[1023];
}

__global__ __launch_bounds__(256) void scanC_kernel(const int* __restrict__ cnt,
                                                    const int* __restrict__ bpre,
                                                    int* __restrict__ offs, int M) {
    __shared__ int sm[256];
    int t = threadIdx.x;
    int i = blockIdx.x * 256 + t;
    int v = (i < M) ? cnt[i] : 0;
    sm[t] = v;
    __syncthreads();
    for (int d = 1; d < 256; d <<= 1) {
        int u = 0;
        if (t >= d) u = sm[t - d];
        __syncthreads();
        if (t >= d) sm[t] += u;
        __syncthreads();
    }
    if (i < M) offs[i] = bpre[blockIdx.x] + sm[t] - v;   // exclusive
}

// entry: x = src | (d%DPW)<<20 ; y = norm
__global__ __launch_bounds__(256) void fill16_kernel(const int* __restrict__ src,
                                                     const int* __restrict__ dst,
                                                     const int* __restrict__ offs,
                                                     int* __restrict__ cur,
                                                     const float* __restrict__ dinv,
                                                     int2* __restrict__ csr, int e) {
    int i = blockIdx.x * 256 + threadIdx.x;
    if (i >= e) return;
    int s = src[i], d = dst[i];
    unsigned p = (unsigned)s >> PSH;
    unsigned wq = (unsigned)d / DPW;
    unsigned dm = (unsigned)d - wq * DPW;
    size_t bin = (size_t)wq * NP + p;
    int pos = offs[bin] + atomicAdd(&cur[bin], 1);
    csr[pos] = make_int2(s | (dm << 20), __float_as_int(dinv[s] * dinv[d]));
}

// ---------------- Aggregate: 40KB LDS accumulators, one wq per wave, phase-locked ----
// Grid = ceil(nwq/8) blocks of 512; 4 blocks/CU (LDS 4x40KB=160KB) -> 32 waves/CU.
// One wq per wave -> ~1.2 block generations -> chip-wide partition sweep stays aligned,
// keeping the instantaneous gather footprint ~1-2 partitions (2-4MB, L2-resident).

#define RMW(rk, nk, dk)                                              \
    {                                                                \
        float2 t = acc2[wbase + (dk)][lane];                         \
        t.x += bflo(rk) * (nk);                                      \
        t.y += bfhi(rk) * (nk);                                      \
        acc2[wbase + (dk)][lane] = t;                                \
    }

template <int POOL>
__global__ __launch_bounds__(512) void aggL_kernel(const unsigned* __restrict__ hlb,
                                                   const int* __restrict__ offs,
                                                   const int2* __restrict__ csr,
                                                   const float* __restrict__ dinv,
                                                   const float* __restrict__ bias,
                                                   void* __restrict__ outp,
                                                   const int* __restrict__ batch,
                                                   int n, int nwq) {
    __shared__ float2 acc2[8 * DPW][64];             // 40KB
    const int lane = threadIdx.x & 63;
    const int w = __builtin_amdgcn_readfirstlane(threadIdx.x >> 6);   // 0..7
    const int wq = blockIdx.x * 8 + w;
    const int wbase = w * DPW;
    const float2 bv = ((const float2*)bias)[lane];
    if (wq >= nwq) return;

    #pragma unroll
    for (int dl = 0; dl < DPW; dl++)
        acc2[wbase + dl][lane] = make_float2(0.0f, 0.0f);

    const int e0 = offs[wq * NP];
    const int e1 = offs[wq * NP + NP];
    int e = e0;
    int nb = (e1 - e0) >> 3;

    int2 c0, c1, c2, c3, c4, c5, c6, c7;
    if (nb > 0) {
        c0 = csr[e + 0]; c1 = csr[e + 1]; c2 = csr[e + 2]; c3 = csr[e + 3];
        c4 = csr[e + 4]; c5 = csr[e + 5]; c6 = csr[e + 6]; c7 = csr[e + 7];
    }
    for (int b = 0; b < nb; b++) {
        unsigned r0 = hlb[((size_t)(c0.x & 0xFFFFF) << 6) + lane];
        unsigned r1 = hlb[((size_t)(c1.x & 0xFFFFF) << 6) + lane];
        unsigned r2 = hlb[((size_t)(c2.x & 0xFFFFF) << 6) + lane];
        unsigned r3 = hlb[((size_t)(c3.x & 0xFFFFF) << 6) + lane];
        unsigned r4 = hlb[((size_t)(c4.x & 0xFFFFF) << 6) + lane];
        unsigned r5 = hlb[((size_t)(c5.x & 0xFFFFF) << 6) + lane];
        unsigned r6 = hlb[((size_t)(c6.x & 0xFFFFF) << 6) + lane];
        unsigned r7 = hlb[((size_t)(c7.x & 0xFFFFF) << 6) + lane];
        float n0 = __int_as_float(c0.y), n1 = __int_as_float(c1.y);
        float n2 = __int_as_float(c2.y), n3 = __int_as_float(c3.y);
        float n4 = __int_as_float(c4.y), n5 = __int_as_float(c5.y);
        float n6 = __int_as_float(c6.y), n7 = __int_as_float(c7.y);
        int d0 = (unsigned)c0.x >> 20, d1 = (unsigned)c1.x >> 20;
        int d2 = (unsigned)c2.x >> 20, d3 = (unsigned)c3.x >> 20;
        int d4 = (unsigned)c4.x >> 20, d5 = (unsigned)c5.x >> 20;
        int d6 = (unsigned)c6.x >> 20, d7 = (unsigned)c7.x >> 20;
        e += 8;
        if (b + 1 < nb) {
            c0 = csr[e + 0]; c1 = csr[e + 1]; c2 = csr[e + 2]; c3 = csr[e + 3];
            c4 = csr[e + 4]; c5 = csr[e + 5]; c6 = csr[e + 6]; c7 = csr[e + 7];
        }
        RMW(r0, n0, d0); RMW(r1, n1, d1); RMW(r2, n2, d2); RMW(r3, n3, d3);
        RMW(r4, n4, d4); RMW(r5, n5, d5); RMW(r6, n6, d6); RMW(r7, n7, d7);
    }
    for (; e < e1; e++) {
        int2 c = csr[e];
        unsigned r = hlb[((size_t)(c.x & 0xFFFFF) << 6) + lane];
        float nf = __int_as_float(c.y);
        int dl = (unsigned)c.x >> 20;
        RMW(r, nf, dl);
    }

    // epilogue: self loop + bias + relu (wave-exclusive dst range, no barrier)
    #pragma unroll
    for (int dl = 0; dl < DPW; dl++) {
        int d = wq * DPW + dl;
        if (d < n) {
            float2 t = acc2[wbase + dl][lane];
            float di = dinv[d];
            float sw = di * di;
            unsigned s = hlb[((size_t)d << 6) + lane];
            float rx = fmaxf(t.x + bflo(s) * sw + bv.x, 0.0f);
            float ry = fmaxf(t.y + bfhi(s) * sw + bv.y, 0.0f);
            if (POOL) {
                int g = batch[d];
                float* out = (float*)outp;
                atomicMax((int*)&out[(size_t)g * F + 2 * lane + 0], __float_as_int(rx));
                atomicMax((int*)&out[(size_t)g * F + 2 * lane + 1], __float_as_int(ry));
            } else {
                unsigned lo = (unsigned)f32_to_bf16_rne(rx);
                unsigned hi = (unsigned)f32_to_bf16_rne(ry);
                ((unsigned*)outp)[((size_t)d << 6) + lane] = lo | (hi << 16);
            }
        }
    }
}

// ---------------- MLP head + log_softmax ----------------

__global__ __launch_bounds__(128) void mlp_kernel(const float* __restrict__ pooled,
                                                  const float* __restrict__ Wp1,
                                                  const float* __restrict__ bp1,
                                                  const float* __restrict__ Wp2,
                                                  const float* __restrict__ bp2,
                                                  float* __restrict__ out) {
    __shared__ float pl[F];
    __shared__ float s0[2], s1[2];
    int g = blockIdx.x, t = threadIdx.x;
    pl[t] = pooled[(size_t)g * F + t];
    __syncthreads();
    float a = bp1[t];
    #pragma unroll 8
    for (int k = 0; k < F; k++) a += pl[k] * Wp1[k * F + t];
    float p0 = a * Wp2[t * 2 + 0];
    float p1 = a * Wp2[t * 2 + 1];
    #pragma unroll
    for (int d = 32; d > 0; d >>= 1) {
        p0 += __shfl_down(p0, d, 64);
        p1 += __shfl_down(p1, d, 64);
    }
    if ((t & 63) == 0) { s0[t >> 6] = p0; s1[t >> 6] = p1; }
    __syncthreads();
    if (t == 0) {
        float l0 = s0[0] + s0[1] + bp2[0];
        float l1 = s1[0] + s1[1] + bp2[1];
        float m = fmaxf(l0, l1);
        float lse = m + logf(expf(l0 - m) + expf(l1 - m));
        out[g * 2 + 0] = l0 - lse;
        out[g * 2 + 1] = l1 - lse;
    }
}

// ---------------- launch ----------------

extern "C" void kernel_launch(void* const* d_in, const int* in_sizes, int n_in,
                              void* d_out, int out_size, void* d_ws, size_t ws_size,
                              hipStream_t stream) {
    const float* x    = (const float*)d_in[0];
    const int*   ei   = (const int*)d_in[1];
    const int*   batch= (const int*)d_in[2];
    const float* W1 = (const float*)d_in[3];  const float* b1 = (const float*)d_in[4];
    const float* W2 = (const float*)d_in[5];  const float* b2 = (const float*)d_in[6];
    const float* W3 = (const float*)d_in[7];  const float* b3 = (const float*)d_in[8];
    const float* Wp1= (const float*)d_in[9];  const float* bp1= (const float*)d_in[10];
    const float* Wp2= (const float*)d_in[11]; const float* bp2= (const float*)d_in[12];

    const int N = in_sizes[0] / F;
    const int E = in_sizes[1] / 2;
    const int G = out_size / 2;
    const int* srcp = ei;
    const int* dstp = ei + E;
    const int eb = (E + 255) / 256;
    const int nb = (N + 255) / 256;

    const int nwq = (N + DPW - 1) / DPW;
    const int nblocks = (nwq + 7) / 8;           // aggL blocks
    const size_t M = (size_t)nwq * NP;           // bins
    const int nblkM = (int)((M + 255) / 256);

    char* w = (char*)d_ws;
    size_t off = 0;
    auto alloc = [&](size_t bytes) -> void* {
        void* p = w + off;
        off = (off + bytes + 255) & ~(size_t)255;
        return p;
    };
    unsigned short* xb   = (unsigned short*)alloc((size_t)N * F * 2);
    unsigned short* hlb  = (unsigned short*)alloc((size_t)N * F * 2);
    unsigned short* hab  = (unsigned short*)alloc((size_t)N * F * 2);
    unsigned short* Wt1  = (unsigned short*)alloc((size_t)F * F * 2);
    unsigned short* Wt2  = (unsigned short*)alloc((size_t)F * F * 2);
    unsigned short* Wt3  = (unsigned short*)alloc((size_t)F * F * 2);
    int*   cnt16  = (int*)alloc(M * 4);
    int*   cur16  = (int*)alloc(M * 4);
    int*   offs16 = (int*)alloc((M + 1) * 4);
    int*   bsum   = (int*)alloc((size_t)nblkM * 4);
    int*   bpre   = (int*)alloc((size_t)nblkM * 4);
    int*   cntd   = (int*)alloc((size_t)N * 4);
    float* dinv   = (float*)alloc((size_t)N * 4);
    int2*  csr16  = (int2*)alloc((size_t)E * 8);
    float* pooled = (float*)alloc((size_t)G * F * 4);

    hipMemsetAsync(cnt16, 0, M * 4, stream);
    hipMemsetAsync(cur16, 0, M * 4, stream);
    hipMemsetAsync(cntd,  0, (size_t)N * 4, stream);
    hipMemsetAsync(pooled, 0, (size_t)G * F * 4, stream);

    cvtx_kernel<<<2048, 256, 0, stream>>>((const float4*)x, (ushort4*)xb, (long)N * F / 4);
    cvtw_kernel<<<F, F, 0, stream>>>(W1, Wt1);
    cvtw_kernel<<<F, F, 0, stream>>>(W2, Wt2);
    cvtw_kernel<<<F, F, 0, stream>>>(W3, Wt3);

    count16_kernel<<<eb, 256, 0, stream>>>(srcp, dstp, cnt16, cntd, E);
    dinv_kernel<<<nb, 256, 0, stream>>>(cntd, dinv, N);
    scanA_kernel<<<nblkM, 256, 0, stream>>>(cnt16, bsum, (int)M);
    scanB_kernel<<<1, 1024, 0, stream>>>(bsum, bpre, offs16, nblkM, (int)M);
    scanC_kernel<<<nblkM, 256, 0, stream>>>(cnt16, bpre, offs16, (int)M);
    fill16_kernel<<<eb, 256, 0, stream>>>(srcp, dstp, offs16, cur16, dinv, csr16, E);

    const int gb = (N + 63) / 64;

    gemm_mfma<<<gb, 256, 0, stream>>>(xb, Wt1, hlb, N);
    aggL_kernel<0><<<nblocks, 512, 0, stream>>>((const unsigned*)hlb, offs16, csr16, dinv, b1, hab, nullptr, N, nwq);
    gemm_mfma<<<gb, 256, 0, stream>>>(hab, Wt2, hlb, N);
    aggL_kernel<0><<<nblocks, 512, 0, stream>>>((const unsigned*)hlb, offs16, csr16, dinv, b2, hab, nullptr, N, nwq);
    gemm_mfma<<<gb, 256, 0, stream>>>(hab, Wt3, hlb, N);
    aggL_kernel<1><<<nblocks, 512, 0, stream>>>((const unsigned*)hlb, offs16, csr16, dinv, b3, pooled, batch, N, nwq);

    mlp_kernel<<<G, 128, 0, stream>>>(pooled, Wp1, bp1, Wp2, bp2, (float*)d_out);
}

// Round 16
// 622.033 us; speedup vs baseline: 1.0193x; 1.0193x over previous
//
#include <hip/hip_runtime.h>

#define F 128
#define PSH 13            // src partition = s >> 13 (8192 nodes = 1MB fp8), p in [0,13)
#define NP 13
#define DPW 10            // dst rows per wave; 8 waves * 10 * 512B = 40KB LDS

typedef __attribute__((ext_vector_type(8))) short bf16x8;
typedef __attribute__((ext_vector_type(4))) float f32x4;
typedef __attribute__((ext_vector_type(2))) float vf2;

#if defined(__has_builtin)
#if __has_builtin(__builtin_amdgcn_cvt_pk_f32_fp8) && __has_builtin(__builtin_amdgcn_cvt_pk_fp8_f32)
#define HW_FP8 1
#endif
#endif

// ---------------- bf16 helpers ----------------

__device__ __forceinline__ unsigned short f32_to_bf16_rne(float x) {
    unsigned u = __float_as_uint(x);
    unsigned r = (u + 0x7fffu + ((u >> 16) & 1u)) >> 16;   // round to nearest even
    return (unsigned short)r;
}

__device__ __forceinline__ float bfhi(unsigned v) { return __uint_as_float(v & 0xffff0000u); }
__device__ __forceinline__ float bflo(unsigned v) { return __uint_as_float(v << 16); }

// ---------------- fp8 e4m3 (OCP) helpers ----------------

__device__ __forceinline__ unsigned char f32_to_fp8(float x) {
#ifdef HW_FP8
    int p = __builtin_amdgcn_cvt_pk_fp8_f32(x, x, 0, false);
    return (unsigned char)(p & 0xFF);
#else
    float ax = fminf(fabsf(x), 448.0f);
    unsigned s = (__float_as_uint(x) >> 31) << 7;
    if (ax < 0.0009765625f) return (unsigned char)s;   // < 2^-10 -> 0
    int e;
    float mant = frexpf(ax, &e);       // ax = mant*2^e, mant in [0.5,1)
    int E = e - 1;
    unsigned bits;
    if (E < -6) {
        bits = (unsigned)rintf(ax * 512.0f);           // denormal units of 2^-9 (q=8 rolls into min normal)
    } else {
        unsigned m = (unsigned)rintf((2.0f * mant - 1.0f) * 8.0f);
        unsigned ee = (unsigned)(E + 7);
        if (m == 8) { m = 0; ee += 1; }
        if (ee >= 15 && (ee > 15 || m >= 7)) { ee = 15; m = 6; }   // sat at 448, avoid NaN
        bits = (ee << 3) | m;
    }
    return (unsigned char)(s | bits);
#endif
}

__device__ __forceinline__ float2 fp8x2_to_f32(unsigned short v) {
#ifdef HW_FP8
    vf2 r = __builtin_amdgcn_cvt_pk_f32_fp8((int)(unsigned)v, false);
    return make_float2(r[0], r[1]);
#else
    float2 o;
    #pragma unroll
    for (int i = 0; i < 2; i++) {
        unsigned b = (v >> (8 * i)) & 0xFF;
        unsigned s = b >> 7, e = (b >> 3) & 15, m = b & 7;
        float fn = __uint_as_float((s << 31) | ((e + 120) << 23) | (m << 20));
        float fd = (s ? -1.0f : 1.0f) * (float)m * 0.001953125f;
        float val = e ? fn : fd;
        if (i == 0) o.x = val; else o.y = val;
    }
    return o;
#endif
}

// ---------------- converts ----------------

__global__ __launch_bounds__(256) void cvtx_kernel(const float4* __restrict__ x4,
                                                   ushort4* __restrict__ xb4, long n4) {
    long stride = (long)gridDim.x * 256;
    for (long i = blockIdx.x * 256 + threadIdx.x; i < n4; i += stride) {
        float4 v = x4[i];
        ushort4 o;
        o.x = f32_to_bf16_rne(v.x);
        o.y = f32_to_bf16_rne(v.y);
        o.z = f32_to_bf16_rne(v.z);
        o.w = f32_to_bf16_rne(v.w);
        xb4[i] = o;
    }
}

__global__ __launch_bounds__(128) void cvtw_kernel(const float* __restrict__ W,
                                                   unsigned short* __restrict__ Wt) {
    int c = blockIdx.x, k = threadIdx.x;
    Wt[c * F + k] = f32_to_bf16_rne(W[k * F + c]);
}

// ---------------- MFMA GEMM: fp8 output (for aggregation gather) ----------------

__global__ __launch_bounds__(256) void gemm_mfma(const unsigned short* __restrict__ hb,
                                                 const unsigned short* __restrict__ Wt,
                                                 unsigned char* __restrict__ outb8, int n) {
    __shared__ unsigned char smb[4][16][F];
    const int tid = threadIdx.x;
    const int w = tid >> 6, lane = tid & 63;
    const int r = lane & 15, kg = lane >> 4;
    const long base = (long)blockIdx.x * 64 + w * 16;

    int arow = (int)(base + r);
    if (arow >= n) arow = n - 1;
    const bf16x8* __restrict__ arowp = (const bf16x8*)(hb + (size_t)arow * F);

    f32x4 acc[8] = {};
    #pragma unroll
    for (int c = 0; c < 4; c++) {
        bf16x8 a = arowp[c * 4 + kg];
        #pragma unroll
        for (int t = 0; t < 8; t++) {
            bf16x8 b = *(const bf16x8*)(Wt + (size_t)(t * 16 + r) * F + c * 32 + kg * 8);
            acc[t] = __builtin_amdgcn_mfma_f32_16x16x32_bf16(a, b, acc[t], 0, 0, 0);
        }
    }

    #pragma unroll
    for (int t = 0; t < 8; t++)
        #pragma unroll
        for (int j = 0; j < 4; j++)
            smb[w][kg * 4 + j][t * 16 + r] = f32_to_fp8(acc[t][j]);
    #pragma unroll
    for (int it = 0; it < 4; it++) {
        int row = it * 4 + kg;
        long grow = base + row;
        if (grow < n) {
            uint2 v = *(uint2*)&smb[w][row][r * 8];
            *(uint2*)(outb8 + (size_t)grow * F + r * 8) = v;
        }
    }
}

// ---------------- build: edges binned by (wq = d/DPW, src partition) ----------

__global__ __launch_bounds__(256) void count16_kernel(const int* __restrict__ src,
                                                      const int* __restrict__ dst,
                                                      int* __restrict__ cnt,
                                                      int* __restrict__ cntd, int e) {
    int i = blockIdx.x * 256 + threadIdx.x;
    if (i >= e) return;
    int s = src[i], d = dst[i];
    unsigned p = (unsigned)s >> PSH;
    atomicAdd(&cnt[(size_t)((unsigned)d / DPW) * NP + p], 1);
    atomicAdd(&cntd[d], 1);
}

__global__ __launch_bounds__(256) void dinv_kernel(const int* __restrict__ cnt,
                                                   float* __restrict__ dinv, int n) {
    int i = blockIdx.x * 256 + threadIdx.x;
    if (i < n) dinv[i] = rsqrtf((float)(cnt[i] + 1));
}

// 3-phase coalesced scan over M elements
__global__ __launch_bounds__(256) void scanA_kernel(const int* __restrict__ cnt,
                                                    int* __restrict__ bsum, int M) {
    __shared__ int sm[256];
    int t = threadIdx.x;
    int i = blockIdx.x * 256 + t;
    int v = (i < M) ? cnt[i] : 0;
    sm[t] = v;
    __syncthreads();
    for (int d = 128; d > 0; d >>= 1) {
        if (t < d) sm[t] += sm[t + d];
        __syncthreads();
    }
    if (t == 0) bsum[blockIdx.x] = sm[0];
}

__global__ __launch_bounds__(1024) void scanB_kernel(const int* __restrict__ bsum,
                                                     int* __restrict__ bpre,
                                                     int* __restrict__ offs, int nb, int M) {
    __shared__ int sm[1024];
    int t = threadIdx.x;
    int chunk = (nb + 1023) >> 10;
    int b = t * chunk;
    int e = b + chunk; if (e > nb) e = nb;
    int s = 0;
    for (int i = b; i < e; i++) s += bsum[i];
    sm[t] = s;
    __syncthreads();
    for (int d = 1; d < 1024; d <<= 1) {
        int v = 0;
        if (t >= d) v = sm[t - d];
        __syncthreads();
        if (t >= d) sm[t] += v;
        __syncthreads();
    }
    int run = (t == 0) ? 0 : sm[t - 1];
    for (int i = b; i < e; i++) { bpre[i] = run; run += bsum[i]; }
    if (t == 1023) offs[M] = sm[1023];
}

__global__ __launch_bounds__(256) void scanC_kernel(const int* __restrict__ cnt,
                                                    const int* __restrict__ bpre,
                                                    int* __restrict__ offs, int M) {
    __shared__ int sm[256];
    int t = threadIdx.x;
    int i = blockIdx.x * 256 + t;
    int v = (i < M) ? cnt[i] : 0;
    sm[t] = v;
    __syncthreads();
    for (int d = 1; d < 256; d <<= 1) {
        int u = 0;
        if (t >= d) u = sm[t - d];
        __syncthreads();
        if (t >= d) sm[t] += u;
        __syncthreads();
    }
    if (i < M) offs[i] = bpre[blockIdx.x] + sm[t] - v;   // exclusive
}

// entry: x = src | (d%DPW)<<20 ; y = norm
__global__ __launch_bounds__(256) void fill16_kernel(const int* __restrict__ src,
                                                     const int* __restrict__ dst,
                                                     const int* __restrict__ offs,
                                                     int* __restrict__ cur,
                                                     const float* __restrict__ dinv,
                                                     int2* __restrict__ csr, int e) {
    int i = blockIdx.x * 256 + threadIdx.x;
    if (i >= e) return;
    int s = src[i], d = dst[i];
    unsigned p = (unsigned)s >> PSH;
    unsigned wq = (unsigned)d / DPW;
    unsigned dm = (unsigned)d - wq * DPW;
    size_t bin = (size_t)wq * NP + p;
    int pos = offs[bin] + atomicAdd(&cur[bin], 1);
    csr[pos] = make_int2(s | (dm << 20), __float_as_int(dinv[s] * dinv[d]));
}

// ---------------- Aggregate: fp8 gather (1 line/row), f32 LDS accumulators ----------

#define RMW(fk, nk, dk)                                              \
    {                                                                \
        float2 t = acc2[wbase + (dk)][lane];                         \
        t.x += fk.x * (nk);                                          \
        t.y += fk.y * (nk);                                          \
        acc2[wbase + (dk)][lane] = t;                                \
    }

template <int POOL>
__global__ __launch_bounds__(512) void aggL_kernel(const unsigned short* __restrict__ hl8,
                                                   const int* __restrict__ offs,
                                                   const int2* __restrict__ csr,
                                                   const float* __restrict__ dinv,
                                                   const float* __restrict__ bias,
                                                   void* __restrict__ outp,
                                                   const int* __restrict__ batch,
                                                   int n, int nwq) {
    __shared__ float2 acc2[8 * DPW][64];             // 40KB
    const int lane = threadIdx.x & 63;
    const int w = __builtin_amdgcn_readfirstlane(threadIdx.x >> 6);   // 0..7
    const int wq = blockIdx.x * 8 + w;
    const int wbase = w * DPW;
    const float2 bv = ((const float2*)bias)[lane];
    if (wq >= nwq) return;

    #pragma unroll
    for (int dl = 0; dl < DPW; dl++)
        acc2[wbase + dl][lane] = make_float2(0.0f, 0.0f);

    const int e0 = offs[wq * NP];
    const int e1 = offs[wq * NP + NP];
    int e = e0;
    int nb = (e1 - e0) >> 3;

    int2 c0, c1, c2, c3, c4, c5, c6, c7;
    if (nb > 0) {
        c0 = csr[e + 0]; c1 = csr[e + 1]; c2 = csr[e + 2]; c3 = csr[e + 3];
        c4 = csr[e + 4]; c5 = csr[e + 5]; c6 = csr[e + 6]; c7 = csr[e + 7];
    }
    for (int b = 0; b < nb; b++) {
        unsigned short r0 = hl8[((size_t)(c0.x & 0xFFFFF) << 6) + lane];
        unsigned short r1 = hl8[((size_t)(c1.x & 0xFFFFF) << 6) + lane];
        unsigned short r2 = hl8[((size_t)(c2.x & 0xFFFFF) << 6) + lane];
        unsigned short r3 = hl8[((size_t)(c3.x & 0xFFFFF) << 6) + lane];
        unsigned short r4 = hl8[((size_t)(c4.x & 0xFFFFF) << 6) + lane];
        unsigned short r5 = hl8[((size_t)(c5.x & 0xFFFFF) << 6) + lane];
        unsigned short r6 = hl8[((size_t)(c6.x & 0xFFFFF) << 6) + lane];
        unsigned short r7 = hl8[((size_t)(c7.x & 0xFFFFF) << 6) + lane];
        float n0 = __int_as_float(c0.y), n1 = __int_as_float(c1.y);
        float n2 = __int_as_float(c2.y), n3 = __int_as_float(c3.y);
        float n4 = __int_as_float(c4.y), n5 = __int_as_float(c5.y);
        float n6 = __int_as_float(c6.y), n7 = __int_as_float(c7.y);
        int d0 = (unsigned)c0.x >> 20, d1 = (unsigned)c1.x >> 20;
        int d2 = (unsigned)c2.x >> 20, d3 = (unsigned)c3.x >> 20;
        int d4 = (unsigned)c4.x >> 20, d5 = (unsigned)c5.x >> 20;
        int d6 = (unsigned)c6.x >> 20, d7 = (unsigned)c7.x >> 20;
        e += 8;
        if (b + 1 < nb) {
            c0 = csr[e + 0]; c1 = csr[e + 1]; c2 = csr[e + 2]; c3 = csr[e + 3];
            c4 = csr[e + 4]; c5 = csr[e + 5]; c6 = csr[e + 6]; c7 = csr[e + 7];
        }
        float2 f0 = fp8x2_to_f32(r0), f1 = fp8x2_to_f32(r1);
        float2 f2 = fp8x2_to_f32(r2), f3 = fp8x2_to_f32(r3);
        float2 f4 = fp8x2_to_f32(r4), f5 = fp8x2_to_f32(r5);
        float2 f6 = fp8x2_to_f32(r6), f7 = fp8x2_to_f32(r7);
        RMW(f0, n0, d0); RMW(f1, n1, d1); RMW(f2, n2, d2); RMW(f3, n3, d3);
        RMW(f4, n4, d4); RMW(f5, n5, d5); RMW(f6, n6, d6); RMW(f7, n7, d7);
    }
    for (; e < e1; e++) {
        int2 c = csr[e];
        float2 f = fp8x2_to_f32(hl8[((size_t)(c.x & 0xFFFFF) << 6) + lane]);
        float nf = __int_as_float(c.y);
        int dl = (unsigned)c.x >> 20;
        RMW(f, nf, dl);
    }

    // epilogue: self loop + bias + relu (wave-exclusive dst range, no barrier)
    #pragma unroll
    for (int dl = 0; dl < DPW; dl++) {
        int d = wq * DPW + dl;
        if (d < n) {
            float2 t = acc2[wbase + dl][lane];
            float di = dinv[d];
            float sw = di * di;
            float2 sv = fp8x2_to_f32(hl8[((size_t)d << 6) + lane]);
            float rx = fmaxf(t.x + sv.x * sw + bv.x, 0.0f);
            float ry = fmaxf(t.y + sv.y * sw + bv.y, 0.0f);
            if (POOL) {
                int g = batch[d];
                float* out = (float*)outp;
                atomicMax((int*)&out[(size_t)g * F + 2 * lane + 0], __float_as_int(rx));
                atomicMax((int*)&out[(size_t)g * F + 2 * lane + 1], __float_as_int(ry));
            } else {
                unsigned lo = (unsigned)f32_to_bf16_rne(rx);
                unsigned hi = (unsigned)f32_to_bf16_rne(ry);
                ((unsigned*)outp)[((size_t)d << 6) + lane] = lo | (hi << 16);
            }
        }
    }
}

// ---------------- MLP head + log_softmax ----------------

__global__ __launch_bounds__(128) void mlp_kernel(const float* __restrict__ pooled,
                                                  const float* __restrict__ Wp1,
                                                  const float* __restrict__ bp1,
                                                  const float* __restrict__ Wp2,
                                                  const float* __restrict__ bp2,
                                                  float* __restrict__ out) {
    __shared__ float pl[F];
    __shared__ float s0[2], s1[2];
    int g = blockIdx.x, t = threadIdx.x;
    pl[t] = pooled[(size_t)g * F + t];
    __syncthreads();
    float a = bp1[t];
    #pragma unroll 8
    for (int k = 0; k < F; k++) a += pl[k] * Wp1[k * F + t];
    float p0 = a * Wp2[t * 2 + 0];
    float p1 = a * Wp2[t * 2 + 1];
    #pragma unroll
    for (int d = 32; d > 0; d >>= 1) {
        p0 += __shfl_down(p0, d, 64);
        p1 += __shfl_down(p1, d, 64);
    }
    if ((t & 63) == 0) { s0[t >> 6] = p0; s1[t >> 6] = p1; }
    __syncthreads();
    if (t == 0) {
        float l0 = s0[0] + s0[1] + bp2[0];
        float l1 = s1[0] + s1[1] + bp2[1];
        float m = fmaxf(l0, l1);
        float lse = m + logf(expf(l0 - m) + expf(l1 - m));
        out[g * 2 + 0] = l0 - lse;
        out[g * 2 + 1] = l1 - lse;
    }
}

// ---------------- launch ----------------

extern "C" void kernel_launch(void* const* d_in, const int* in_sizes, int n_in,
                              void* d_out, int out_size, void* d_ws, size_t ws_size,
                              hipStream_t stream) {
    const float* x    = (const float*)d_in[0];
    const int*   ei   = (const int*)d_in[1];
    const int*   batch= (const int*)d_in[2];
    const float* W1 = (const float*)d_in[3];  const float* b1 = (const float*)d_in[4];
    const float* W2 = (const float*)d_in[5];  const float* b2 = (const float*)d_in[6];
    const float* W3 = (const float*)d_in[7];  const float* b3 = (const float*)d_in[8];
    const float* Wp1= (const float*)d_in[9];  const float* bp1= (const float*)d_in[10];
    const float* Wp2= (const float*)d_in[11]; const float* bp2= (const float*)d_in[12];

    const int N = in_sizes[0] / F;
    const int E = in_sizes[1] / 2;
    const int G = out_size / 2;
    const int* srcp = ei;
    const int* dstp = ei + E;
    const int eb = (E + 255) / 256;
    const int nb = (N + 255) / 256;

    const int nwq = (N + DPW - 1) / DPW;
    const int nblocks = (nwq + 7) / 8;           // aggL blocks
    const size_t M = (size_t)nwq * NP;           // bins
    const int nblkM = (int)((M + 255) / 256);

    char* w = (char*)d_ws;
    size_t off = 0;
    auto alloc = [&](size_t bytes) -> void* {
        void* p = w + off;
        off = (off + bytes + 255) & ~(size_t)255;
        return p;
    };
    unsigned short* xb   = (unsigned short*)alloc((size_t)N * F * 2);
    unsigned char*  hl8  = (unsigned char*)alloc((size_t)N * F);       // fp8 GEMM out
    unsigned short* hab  = (unsigned short*)alloc((size_t)N * F * 2);  // bf16 layer out
    unsigned short* Wt1  = (unsigned short*)alloc((size_t)F * F * 2);
    unsigned short* Wt2  = (unsigned short*)alloc((size_t)F * F * 2);
    unsigned short* Wt3  = (unsigned short*)alloc((size_t)F * F * 2);
    int*   cnt16  = (int*)alloc(M * 4);
    int*   cur16  = (int*)alloc(M * 4);
    int*   offs16 = (int*)alloc((M + 1) * 4);
    int*   bsum   = (int*)alloc((size_t)nblkM * 4);
    int*   bpre   = (int*)alloc((size_t)nblkM * 4);
    int*   cntd   = (int*)alloc((size_t)N * 4);
    float* dinv   = (float*)alloc((size_t)N * 4);
    int2*  csr16  = (int2*)alloc((size_t)E * 8);
    float* pooled = (float*)alloc((size_t)G * F * 4);

    hipMemsetAsync(cnt16, 0, M * 4, stream);
    hipMemsetAsync(cur16, 0, M * 4, stream);
    hipMemsetAsync(cntd,  0, (size_t)N * 4, stream);
    hipMemsetAsync(pooled, 0, (size_t)G * F * 4, stream);

    cvtx_kernel<<<2048, 256, 0, stream>>>((const float4*)x, (ushort4*)xb, (long)N * F / 4);
    cvtw_kernel<<<F, F, 0, stream>>>(W1, Wt1);
    cvtw_kernel<<<F, F, 0, stream>>>(W2, Wt2);
    cvtw_kernel<<<F, F, 0, stream>>>(W3, Wt3);

    count16_kernel<<<eb, 256, 0, stream>>>(srcp, dstp, cnt16, cntd, E);
    dinv_kernel<<<nb, 256, 0, stream>>>(cntd, dinv, N);
    scanA_kernel<<<nblkM, 256, 0, stream>>>(cnt16, bsum, (int)M);
    scanB_kernel<<<1, 1024, 0, stream>>>(bsum, bpre, offs16, nblkM, (int)M);
    scanC_kernel<<<nblkM, 256, 0, stream>>>(cnt16, bpre, offs16, (int)M);
    fill16_kernel<<<eb, 256, 0, stream>>>(srcp, dstp, offs16, cur16, dinv, csr16, E);

    const int gb = (N + 63) / 64;

    gemm_mfma<<<gb, 256, 0, stream>>>(xb, Wt1, hl8, N);
    aggL_kernel<0><<<nblocks, 512, 0, stream>>>((const unsigned short*)hl8, offs16, csr16, dinv, b1, hab, nullptr, N, nwq);
    gemm_mfma<<<gb, 256, 0, stream>>>(hab, Wt2, hl8, N);
    aggL_kernel<0><<<nblocks, 512, 0, stream>>>((const unsigned short*)hl8, offs16, csr16, dinv, b2, hab, nullptr, N, nwq);
    gemm_mfma<<<gb, 256, 0, stream>>>(hab, Wt3, hl8, N);
    aggL_kernel<1><<<nblocks, 512, 0, stream>>>((const unsigned short*)hl8, offs16, csr16, dinv, b3, pooled, batch, N, nwq);

    mlp_kernel<<<G, 128, 0, stream>>>(pooled, Wp1, bp1, Wp2, bp2, (float*)d_out);
}

// Round 17
// 584.043 us; speedup vs baseline: 1.0856x; 1.0650x over previous
//
#include <hip/hip_runtime.h>

#define F 128
#define PSH 13            // src partition = s >> 13 (8192 nodes = 1MB fp8), p in [0,13)
#define NP 13
#define DPW 10            // dst rows per wave; 8 waves * 10 * 512B = 40KB LDS
#define AGRID 1024        // persistent aggL grid: 4 blocks/CU * 256 CU

typedef __attribute__((ext_vector_type(8))) short bf16x8;
typedef __attribute__((ext_vector_type(4))) float f32x4;
typedef __attribute__((ext_vector_type(2))) float vf2;

#if defined(__has_builtin)
#if __has_builtin(__builtin_amdgcn_cvt_pk_f32_fp8) && __has_builtin(__builtin_amdgcn_cvt_pk_fp8_f32)
#define HW_FP8 1
#endif
#endif

// ---------------- bf16 helpers ----------------

__device__ __forceinline__ unsigned short f32_to_bf16_rne(float x) {
    unsigned u = __float_as_uint(x);
    unsigned r = (u + 0x7fffu + ((u >> 16) & 1u)) >> 16;   // round to nearest even
    return (unsigned short)r;
}

__device__ __forceinline__ float bfhi(unsigned v) { return __uint_as_float(v & 0xffff0000u); }
__device__ __forceinline__ float bflo(unsigned v) { return __uint_as_float(v << 16); }

// ---------------- fp8 e4m3 (OCP) helpers ----------------

__device__ __forceinline__ unsigned char f32_to_fp8(float x) {
#ifdef HW_FP8
    int p = __builtin_amdgcn_cvt_pk_fp8_f32(x, x, 0, false);
    return (unsigned char)(p & 0xFF);
#else
    float ax = fminf(fabsf(x), 448.0f);
    unsigned s = (__float_as_uint(x) >> 31) << 7;
    if (ax < 0.0009765625f) return (unsigned char)s;   // < 2^-10 -> 0
    int e;
    float mant = frexpf(ax, &e);       // ax = mant*2^e, mant in [0.5,1)
    int E = e - 1;
    unsigned bits;
    if (E < -6) {
        bits = (unsigned)rintf(ax * 512.0f);           // denormal units of 2^-9
    } else {
        unsigned m = (unsigned)rintf((2.0f * mant - 1.0f) * 8.0f);
        unsigned ee = (unsigned)(E + 7);
        if (m == 8) { m = 0; ee += 1; }
        if (ee >= 15 && (ee > 15 || m >= 7)) { ee = 15; m = 6; }   // sat at 448
        bits = (ee << 3) | m;
    }
    return (unsigned char)(s | bits);
#endif
}

__device__ __forceinline__ float2 fp8x2_to_f32(unsigned short v) {
#ifdef HW_FP8
    vf2 r = __builtin_amdgcn_cvt_pk_f32_fp8((int)(unsigned)v, false);
    return make_float2(r[0], r[1]);
#else
    float2 o;
    #pragma unroll
    for (int i = 0; i < 2; i++) {
        unsigned b = (v >> (8 * i)) & 0xFF;
        unsigned s = b >> 7, e = (b >> 3) & 15, m = b & 7;
        float fn = __uint_as_float((s << 31) | ((e + 120) << 23) | (m << 20));
        float fd = (s ? -1.0f : 1.0f) * (float)m * 0.001953125f;
        float val = e ? fn : fd;
        if (i == 0) o.x = val; else o.y = val;
    }
    return o;
#endif
}

// ---------------- converts ----------------

__global__ __launch_bounds__(128) void cvtw_kernel(const float* __restrict__ W,
                                                   unsigned short* __restrict__ Wt) {
    int c = blockIdx.x, k = threadIdx.x;
    Wt[c * F + k] = f32_to_bf16_rne(W[k * F + c]);
}

// ---------------- MFMA GEMM: bf16 or f32 input, fp8 output ----------------

template <int F32IN>
__global__ __launch_bounds__(256) void gemm_mfma(const void* __restrict__ hin,
                                                 const unsigned short* __restrict__ Wt,
                                                 unsigned char* __restrict__ outb8, int n) {
    __shared__ unsigned char smb[4][16][F];
    const int tid = threadIdx.x;
    const int w = tid >> 6, lane = tid & 63;
    const int r = lane & 15, kg = lane >> 4;
    const long base = (long)blockIdx.x * 64 + w * 16;

    int arow = (int)(base + r);
    if (arow >= n) arow = n - 1;

    f32x4 acc[8] = {};
    #pragma unroll
    for (int c = 0; c < 4; c++) {
        bf16x8 a;
        if (F32IN) {
            const float* ap = (const float*)hin + (size_t)arow * F + c * 32 + kg * 8;
            float4 v0 = *(const float4*)ap;
            float4 v1 = *(const float4*)(ap + 4);
            a[0] = (short)f32_to_bf16_rne(v0.x);
            a[1] = (short)f32_to_bf16_rne(v0.y);
            a[2] = (short)f32_to_bf16_rne(v0.z);
            a[3] = (short)f32_to_bf16_rne(v0.w);
            a[4] = (short)f32_to_bf16_rne(v1.x);
            a[5] = (short)f32_to_bf16_rne(v1.y);
            a[6] = (short)f32_to_bf16_rne(v1.z);
            a[7] = (short)f32_to_bf16_rne(v1.w);
        } else {
            a = ((const bf16x8*)((const unsigned short*)hin + (size_t)arow * F))[c * 4 + kg];
        }
        #pragma unroll
        for (int t = 0; t < 8; t++) {
            bf16x8 b = *(const bf16x8*)(Wt + (size_t)(t * 16 + r) * F + c * 32 + kg * 8);
            acc[t] = __builtin_amdgcn_mfma_f32_16x16x32_bf16(a, b, acc[t], 0, 0, 0);
        }
    }

    #pragma unroll
    for (int t = 0; t < 8; t++)
        #pragma unroll
        for (int j = 0; j < 4; j++)
            smb[w][kg * 4 + j][t * 16 + r] = f32_to_fp8(acc[t][j]);
    #pragma unroll
    for (int it = 0; it < 4; it++) {
        int row = it * 4 + kg;
        long grow = base + row;
        if (grow < n) {
            uint2 v = *(uint2*)&smb[w][row][r * 8];
            *(uint2*)(outb8 + (size_t)grow * F + r * 8) = v;
        }
    }
}

// ---------------- build: edges binned by (wq = d/DPW, src partition) ----------

__global__ __launch_bounds__(256) void count16_kernel(const int* __restrict__ src,
                                                      const int* __restrict__ dst,
                                                      int* __restrict__ cnt,
                                                      int* __restrict__ cntd, int e) {
    int i = blockIdx.x * 256 + threadIdx.x;
    if (i >= e) return;
    int s = src[i], d = dst[i];
    unsigned p = (unsigned)s >> PSH;
    atomicAdd(&cnt[(size_t)((unsigned)d / DPW) * NP + p], 1);
    atomicAdd(&cntd[d], 1);
}

__global__ __launch_bounds__(256) void dinv_kernel(const int* __restrict__ cnt,
                                                   float* __restrict__ dinv, int n) {
    int i = blockIdx.x * 256 + threadIdx.x;
    if (i < n) dinv[i] = rsqrtf((float)(cnt[i] + 1));
}

// 3-phase coalesced scan over M elements
__global__ __launch_bounds__(256) void scanA_kernel(const int* __restrict__ cnt,
                                                    int* __restrict__ bsum, int M) {
    __shared__ int sm[256];
    int t = threadIdx.x;
    int i = blockIdx.x * 256 + t;
    int v = (i < M) ? cnt[i] : 0;
    sm[t] = v;
    __syncthreads();
    for (int d = 128; d > 0; d >>= 1) {
        if (t < d) sm[t] += sm[t + d];
        __syncthreads();
    }
    if (t == 0) bsum[blockIdx.x] = sm[0];
}

__global__ __launch_bounds__(1024) void scanB_kernel(const int* __restrict__ bsum,
                                                     int* __restrict__ bpre,
                                                     int* __restrict__ offs, int nb, int M) {
    __shared__ int sm[1024];
    int t = threadIdx.x;
    int chunk = (nb + 1023) >> 10;
    int b = t * chunk;
    int e = b + chunk; if (e > nb) e = nb;
    int s = 0;
    for (int i = b; i < e; i++) s += bsum[i];
    sm[t] = s;
    __syncthreads();
    for (int d = 1; d < 1024; d <<= 1) {
        int v = 0;
        if (t >= d) v = sm[t - d];
        __syncthreads();
        if (t >= d) sm[t] += v;
        __syncthreads();
    }
    int run = (t == 0) ? 0 : sm[t - 1];
    for (int i = b; i < e; i++) { bpre[i] = run; run += bsum[i]; }
    if (t == 1023) offs[M] = sm[1023];
}

__global__ __launch_bounds__(256) void scanC_kernel(const int* __restrict__ cnt,
                                                    const int* __restrict__ bpre,
                                                    int* __restrict__ offs, int M) {
    __shared__ int sm[256];
    int t = threadIdx.x;
    int i = blockIdx.x * 256 + t;
    int v = (i < M) ? cnt[i] : 0;
    sm[t] = v;
    __syncthreads();
    for (int d = 1; d < 256; d <<= 1) {
        int u = 0;
        if (t >= d) u = sm[t - d];
        __syncthreads();
        if (t >= d) sm[t] += u;
        __syncthreads();
    }
    if (i < M) offs[i] = bpre[blockIdx.x] + sm[t] - v;   // exclusive
}

// entry: x = src | (d%DPW)<<20 ; y = norm
__global__ __launch_bounds__(256) void fill16_kernel(const int* __restrict__ src,
                                                     const int* __restrict__ dst,
                                                     const int* __restrict__ offs,
                                                     int* __restrict__ cur,
                                                     const float* __restrict__ dinv,
                                                     int2* __restrict__ csr, int e) {
    int i = blockIdx.x * 256 + threadIdx.x;
    if (i >= e) return;
    int s = src[i], d = dst[i];
    unsigned p = (unsigned)s >> PSH;
    unsigned wq = (unsigned)d / DPW;
    unsigned dm = (unsigned)d - wq * DPW;
    size_t bin = (size_t)wq * NP + p;
    int pos = offs[bin] + atomicAdd(&cur[bin], 1);
    csr[pos] = make_int2(s | (dm << 20), __float_as_int(dinv[s] * dinv[d]));
}

// ---------------- Aggregate: persistent, fp8 gather, f32 LDS accumulators ----------

#define RMW(fk, nk, dk)                                              \
    {                                                                \
        float2 t = acc2[wbase + (dk)][lane];                         \
        t.x += fk.x * (nk);                                          \
        t.y += fk.y * (nk);                                          \
        acc2[wbase + (dk)][lane] = t;                                \
    }

template <int POOL>
__global__ __launch_bounds__(512) void aggL_kernel(const unsigned short* __restrict__ hl8,
                                                   const int* __restrict__ offs,
                                                   const int2* __restrict__ csr,
                                                   const float* __restrict__ dinv,
                                                   const float* __restrict__ bias,
                                                   void* __restrict__ outp,
                                                   const int* __restrict__ batch,
                                                   int n, int nwq) {
    __shared__ float2 acc2[8 * DPW][64];             // 40KB
    const int lane = threadIdx.x & 63;
    const int w = __builtin_amdgcn_readfirstlane(threadIdx.x >> 6);   // 0..7
    const int wbase = w * DPW;
    const float2 bv = ((const float2*)bias)[lane];

    for (int wq = blockIdx.x * 8 + w; wq < nwq; wq += AGRID * 8) {
        #pragma unroll
        for (int dl = 0; dl < DPW; dl++)
            acc2[wbase + dl][lane] = make_float2(0.0f, 0.0f);

        const int e0 = offs[wq * NP];
        const int e1 = offs[wq * NP + NP];
        int e = e0;
        int nb = (e1 - e0) >> 3;

        int2 c0, c1, c2, c3, c4, c5, c6, c7;
        if (nb > 0) {
            c0 = csr[e + 0]; c1 = csr[e + 1]; c2 = csr[e + 2]; c3 = csr[e + 3];
            c4 = csr[e + 4]; c5 = csr[e + 5]; c6 = csr[e + 6]; c7 = csr[e + 7];
        }
        for (int b = 0; b < nb; b++) {
            unsigned short r0 = hl8[((size_t)(c0.x & 0xFFFFF) << 6) + lane];
            unsigned short r1 = hl8[((size_t)(c1.x & 0xFFFFF) << 6) + lane];
            unsigned short r2 = hl8[((size_t)(c2.x & 0xFFFFF) << 6) + lane];
            unsigned short r3 = hl8[((size_t)(c3.x & 0xFFFFF) << 6) + lane];
            unsigned short r4 = hl8[((size_t)(c4.x & 0xFFFFF) << 6) + lane];
            unsigned short r5 = hl8[((size_t)(c5.x & 0xFFFFF) << 6) + lane];
            unsigned short r6 = hl8[((size_t)(c6.x & 0xFFFFF) << 6) + lane];
            unsigned short r7 = hl8[((size_t)(c7.x & 0xFFFFF) << 6) + lane];
            float n0 = __int_as_float(c0.y), n1 = __int_as_float(c1.y);
            float n2 = __int_as_float(c2.y), n3 = __int_as_float(c3.y);
            float n4 = __int_as_float(c4.y), n5 = __int_as_float(c5.y);
            float n6 = __int_as_float(c6.y), n7 = __int_as_float(c7.y);
            int d0 = (unsigned)c0.x >> 20, d1 = (unsigned)c1.x >> 20;
            int d2 = (unsigned)c2.x >> 20, d3 = (unsigned)c3.x >> 20;
            int d4 = (unsigned)c4.x >> 20, d5 = (unsigned)c5.x >> 20;
            int d6 = (unsigned)c6.x >> 20, d7 = (unsigned)c7.x >> 20;
            e += 8;
            if (b + 1 < nb) {
                c0 = csr[e + 0]; c1 = csr[e + 1]; c2 = csr[e + 2]; c3 = csr[e + 3];
                c4 = csr[e + 4]; c5 = csr[e + 5]; c6 = csr[e + 6]; c7 = csr[e + 7];
            }
            float2 f0 = fp8x2_to_f32(r0), f1 = fp8x2_to_f32(r1);
            float2 f2 = fp8x2_to_f32(r2), f3 = fp8x2_to_f32(r3);
            float2 f4 = fp8x2_to_f32(r4), f5 = fp8x2_to_f32(r5);
            float2 f6 = fp8x2_to_f32(r6), f7 = fp8x2_to_f32(r7);
            RMW(f0, n0, d0); RMW(f1, n1, d1); RMW(f2, n2, d2); RMW(f3, n3, d3);
            RMW(f4, n4, d4); RMW(f5, n5, d5); RMW(f6, n6, d6); RMW(f7, n7, d7);
        }
        for (; e < e1; e++) {
            int2 c = csr[e];
            float2 f = fp8x2_to_f32(hl8[((size_t)(c.x & 0xFFFFF) << 6) + lane]);
            float nf = __int_as_float(c.y);
            int dl = (unsigned)c.x >> 20;
            RMW(f, nf, dl);
        }

        // epilogue: self loop + bias + relu (wave-exclusive dst range, no barrier)
        #pragma unroll
        for (int dl = 0; dl < DPW; dl++) {
            int d = wq * DPW + dl;
            if (d < n) {
                float2 t = acc2[wbase + dl][lane];
                float di = dinv[d];
                float sw = di * di;
                float2 sv = fp8x2_to_f32(hl8[((size_t)d << 6) + lane]);
                float rx = fmaxf(t.x + sv.x * sw + bv.x, 0.0f);
                float ry = fmaxf(t.y + sv.y * sw + bv.y, 0.0f);
                if (POOL) {
                    int g = batch[d];
                    float* out = (float*)outp;
                    atomicMax((int*)&out[(size_t)g * F + 2 * lane + 0], __float_as_int(rx));
                    atomicMax((int*)&out[(size_t)g * F + 2 * lane + 1], __float_as_int(ry));
                } else {
                    unsigned lo = (unsigned)f32_to_bf16_rne(rx);
                    unsigned hi = (unsigned)f32_to_bf16_rne(ry);
                    ((unsigned*)outp)[((size_t)d << 6) + lane] = lo | (hi << 16);
                }
            }
        }
    }
}

// ---------------- MLP head + log_softmax ----------------

__global__ __launch_bounds__(128) void mlp_kernel(const float* __restrict__ pooled,
                                                  const float* __restrict__ Wp1,
                                                  const float* __restrict__ bp1,
                                                  const float* __restrict__ Wp2,
                                                  const float* __restrict__ bp2,
                                                  float* __restrict__ out) {
    __shared__ float pl[F];
    __shared__ float s0[2], s1[2];
    int g = blockIdx.x, t = threadIdx.x;
    pl[t] = pooled[(size_t)g * F + t];
    __syncthreads();
    float a = bp1[t];
    #pragma unroll 8
    for (int k = 0; k < F; k++) a += pl[k] * Wp1[k * F + t];
    float p0 = a * Wp2[t * 2 + 0];
    float p1 = a * Wp2[t * 2 + 1];
    #pragma unroll
    for (int d = 32; d > 0; d >>= 1) {
        p0 += __shfl_down(p0, d, 64);
        p1 += __shfl_down(p1, d, 64);
    }
    if ((t & 63) == 0) { s0[t >> 6] = p0; s1[t >> 6] = p1; }
    __syncthreads();
    if (t == 0) {
        float l0 = s0[0] + s0[1] + bp2[0];
        float l1 = s1[0] + s1[1] + bp2[1];
        float m = fmaxf(l0, l1);
        float lse = m + logf(expf(l0 - m) + expf(l1 - m));
        out[g * 2 + 0] = l0 - lse;
        out[g * 2 + 1] = l1 - lse;
    }
}

// ---------------- launch ----------------

extern "C" void kernel_launch(void* const* d_in, const int* in_sizes, int n_in,
                              void* d_out, int out_size, void* d_ws, size_t ws_size,
                              hipStream_t stream) {
    const float* x    = (const float*)d_in[0];
    const int*   ei   = (const int*)d_in[1];
    const int*   batch= (const int*)d_in[2];
    const float* W1 = (const float*)d_in[3];  const float* b1 = (const float*)d_in[4];
    const float* W2 = (const float*)d_in[5];  const float* b2 = (const float*)d_in[6];
    const float* W3 = (const float*)d_in[7];  const float* b3 = (const float*)d_in[8];
    const float* Wp1= (const float*)d_in[9];  const float* bp1= (const float*)d_in[10];
    const float* Wp2= (const float*)d_in[11]; const float* bp2= (const float*)d_in[12];

    const int N = in_sizes[0] / F;
    const int E = in_sizes[1] / 2;
    const int G = out_size / 2;
    const int* srcp = ei;
    const int* dstp = ei + E;
    const int eb = (E + 255) / 256;
    const int nb = (N + 255) / 256;

    const int nwq = (N + DPW - 1) / DPW;
    const size_t M = (size_t)nwq * NP;           // bins
    const int nblkM = (int)((M + 255) / 256);

    char* w = (char*)d_ws;
    size_t off = 0;
    auto alloc = [&](size_t bytes) -> void* {
        void* p = w + off;
        off = (off + bytes + 255) & ~(size_t)255;
        return p;
    };
    unsigned char*  hl8  = (unsigned char*)alloc((size_t)N * F);       // fp8 GEMM out
    unsigned short* hab  = (unsigned short*)alloc((size_t)N * F * 2);  // bf16 layer out
    unsigned short* Wt1  = (unsigned short*)alloc((size_t)F * F * 2);
    unsigned short* Wt2  = (unsigned short*)alloc((size_t)F * F * 2);
    unsigned short* Wt3  = (unsigned short*)alloc((size_t)F * F * 2);
    int*   cnt16  = (int*)alloc(M * 4);
    int*   cur16  = (int*)alloc(M * 4);
    int*   offs16 = (int*)alloc((M + 1) * 4);
    int*   bsum   = (int*)alloc((size_t)nblkM * 4);
    int*   bpre   = (int*)alloc((size_t)nblkM * 4);
    int*   cntd   = (int*)alloc((size_t)N * 4);
    float* dinv   = (float*)alloc((size_t)N * 4);
    int2*  csr16  = (int2*)alloc((size_t)E * 8);
    float* pooled = (float*)alloc((size_t)G * F * 4);

    hipMemsetAsync(cnt16, 0, M * 4, stream);
    hipMemsetAsync(cur16, 0, M * 4, stream);
    hipMemsetAsync(cntd,  0, (size_t)N * 4, stream);
    hipMemsetAsync(pooled, 0, (size_t)G * F * 4, stream);

    cvtw_kernel<<<F, F, 0, stream>>>(W1, Wt1);
    cvtw_kernel<<<F, F, 0, stream>>>(W2, Wt2);
    cvtw_kernel<<<F, F, 0, stream>>>(W3, Wt3);

    count16_kernel<<<eb, 256, 0, stream>>>(srcp, dstp, cnt16, cntd, E);
    dinv_kernel<<<nb, 256, 0, stream>>>(cntd, dinv, N);
    scanA_kernel<<<nblkM, 256, 0, stream>>>(cnt16, bsum, (int)M);
    scanB_kernel<<<1, 1024, 0, stream>>>(bsum, bpre, offs16, nblkM, (int)M);
    scanC_kernel<<<nblkM, 256, 0, stream>>>(cnt16, bpre, offs16, (int)M);
    fill16_kernel<<<eb, 256, 0, stream>>>(srcp, dstp, offs16, cur16, dinv, csr16, E);

    const int gb = (N + 63) / 64;

    gemm_mfma<1><<<gb, 256, 0, stream>>>(x, Wt1, hl8, N);
    aggL_kernel<0><<<AGRID, 512, 0, stream>>>((const unsigned short*)hl8, offs16, csr16, dinv, b1, hab, nullptr, N, nwq);
    gemm_mfma<0><<<gb, 256, 0, stream>>>(hab, Wt2, hl8, N);
    aggL_kernel<0><<<AGRID, 512, 0, stream>>>((const unsigned short*)hl8, offs16, csr16, dinv, b2, hab, nullptr, N, nwq);
    gemm_mfma<0><<<gb, 256, 0, stream>>>(hab, Wt3, hl8, N);
    aggL_kernel<1><<<AGRID, 512, 0, stream>>>((const unsigned short*)hl8, offs16, csr16, dinv, b3, pooled, batch, N, nwq);

    mlp_kernel<<<G, 128, 0, stream>>>(pooled, Wp1, bp1, Wp2, bp2, (float*)d_out);
}